// Round 2
// baseline (2701.873 us; speedup 1.0000x reference)
//
#include <hip/hip_runtime.h>
#include <climits>

// ---------------------------------------------------------------------------
// Pipeline: per-point MLP + global LN -> per-(pillar,bin) mean -> per-pillar
// 32x64 self-attention -> max-pool -> residual add into sparse_feat.
// Identity used: softmax(q k^T / sqrt(C)) with q=s@Wq, k=s@Wk equals
// softmax(s @ G @ s^T) with G = Wq @ Wk^T / sqrt(C)  (precomputed once).
// ---------------------------------------------------------------------------

__device__ __forceinline__ float point_x(const float* __restrict__ pt,
                                         const float* __restrict__ wc) {
    float x = pt[1] * wc[0];
    x = fmaf(pt[2], wc[1], x);
    x = fmaf(pt[3], wc[2], x);
    x = fmaf(pt[4], wc[3], x);
    x = fmaf(pt[5], wc[4], x);
    x = fmaf(pt[6], wc[5], x);
    x = fmaf(pt[7], wc[6], x);
    x = fmaf(pt[8], wc[7], x);
    return x;
}

// Pass 1: per-channel sum/sumsq of x = points[:,1:9] @ Wc^T over all N points.
__global__ __launch_bounds__(256)
void stats_kernel(const float* __restrict__ pts, const float* __restrict__ Wc,
                  double* __restrict__ gsum, double* __restrict__ gsq, int N)
{
    const int tid = threadIdx.x;
    const int lane = tid & 63;
    const int w = tid >> 6;
    const int c = lane;

    float wc[8];
#pragma unroll
    for (int j = 0; j < 8; ++j) wc[j] = Wc[c * 8 + j];

    double s1 = 0.0, s2 = 0.0;
    const int stride = gridDim.x * 4;
    for (int i = blockIdx.x * 4 + w; i < N; i += stride) {
        const float* pt = pts + (size_t)i * 9;
        const float x = point_x(pt, wc);
        s1 += (double)x;
        s2 += (double)x * (double)x;
    }

    __shared__ double bs[4][64];
    __shared__ double bq[4][64];
    bs[w][c] = s1;
    bq[w][c] = s2;
    __syncthreads();
    if (tid < 64) {
        const double t1 = bs[0][tid] + bs[1][tid] + bs[2][tid] + bs[3][tid];
        const double t2 = bq[0][tid] + bq[1][tid] + bq[2][tid] + bq[3][tid];
        atomicAdd(&gsum[tid], t1);
        atomicAdd(&gsq[tid], t2);
    }
}

// Prep: LN fold (a,b per channel) + Gram matrix G = Wq @ Wk^T / 8.
__global__ __launch_bounds__(256)
void prep_kernel(const double* __restrict__ gsum, const double* __restrict__ gsq,
                 const float* __restrict__ gamma, const float* __restrict__ beta,
                 const float* __restrict__ Wq, const float* __restrict__ Wk,
                 float* __restrict__ ab, float* __restrict__ G, int N)
{
    const int tid = threadIdx.x;
    if (tid < 64) {
        const double mu = gsum[tid] / (double)N;
        const double var = gsq[tid] / (double)N - mu * mu;
        const double a = (double)gamma[tid] / sqrt(var + 0.001);
        ab[tid] = (float)a;
        ab[64 + tid] = (float)((double)beta[tid] - mu * a);
    }
    for (int idx = tid; idx < 4096; idx += 256) {
        const int i = idx >> 6, j = idx & 63;
        float acc = 0.f;
#pragma unroll 4
        for (int cc = 0; cc < 64; ++cc)
            acc = fmaf(Wq[i * 64 + cc], Wk[j * 64 + cc], acc);
        G[idx] = acc * 0.125f;   // fold 1/sqrt(C)
    }
}

// Advance cursor to lower_bound(pinv, target); pinv sorted ascending.
__device__ __forceinline__ int advance_cursor(const int* __restrict__ pinv, int N,
                                              int cur, int target, int lane)
{
    for (;;) {
        const int idx = cur + lane;
        const int v = (idx < N) ? pinv[idx] : INT_MAX;
        const unsigned long long m = __ballot(v < target);
        const int cnt = __popcll(m);
        cur += cnt;
        if (cnt < 64) return cur;
    }
}

// Fused per-pillar kernel: 512 threads = 8 waves; lane = channel c.
// Wave w owns rows r0 = 4w .. 4w+3 of the 32-bin tile.
__global__ __launch_bounds__(512, 4)
void pillar_attn_kernel(const float* __restrict__ pts,
                        const float* __restrict__ sparse_feat,
                        const float* __restrict__ Wc,
                        const float* __restrict__ Wv,
                        const int* __restrict__ pinv,
                        const int* __restrict__ vinv,
                        const int* __restrict__ bov,
                        const int* __restrict__ occ,
                        const float* __restrict__ ab,
                        const float* __restrict__ Gg,
                        float* __restrict__ out,
                        int N, int K)
{
    __shared__ float G_l[64][64];                    // natural layout G[k][c]
    __shared__ float Wv_l[64][64];                   // natural layout Wv[k][c]
    __shared__ __align__(16) float s_[32][68];       // bin means (row-major)
    __shared__ float sT_[64][37];                    // s transposed (stride 37)
    __shared__ __align__(16) float t_[32][68];       // t = s @ G
    __shared__ __align__(16) float v_[32][68];       // v = s @ Wv
    __shared__ __align__(16) float P_[32][36];       // softmax probs
    __shared__ float scnt[32];
    __shared__ float pool[8][64];

    const int tid = threadIdx.x;
    const int lane = tid & 63;
    const int w = tid >> 6;
    const int c = lane;
    const int r0 = w * 4;

    for (int idx = tid; idx < 4096; idx += 512) {
        G_l[idx >> 6][idx & 63] = Gg[idx];
        Wv_l[idx >> 6][idx & 63] = Wv[idx];
    }

    float wc[8];
#pragma unroll
    for (int j = 0; j < 8; ++j) wc[j] = Wc[c * 8 + j];
    const float a_c = ab[c];
    const float b_c = ab[64 + c];

    const int G = gridDim.x;
    const int per = (K + G - 1) / G;
    const int k0 = blockIdx.x * per;
    const int k1 = min(K, k0 + per);
    if (k0 >= k1) return;

    int cur;
    {
        const int p0 = occ[k0];
        int lo = 0, hi = N;
        while (lo < hi) {
            const int mid = (lo + hi) >> 1;
            if (pinv[mid] < p0) lo = mid + 1; else hi = mid;
        }
        cur = lo;
    }
    __syncthreads();

    for (int kk = k0; kk < k1; ++kk) {
        const int p = occ[kk];
        const int i0 = advance_cursor(pinv, N, cur, p, lane);
        cur = advance_cursor(pinv, N, i0, p + 1, lane);
        const int i1 = cur;

        for (int idx = tid; idx < 32 * 68; idx += 512) (&s_[0][0])[idx] = 0.f;
        if (tid < 32) scnt[tid] = 0.f;
        __syncthreads();

        const float sf = sparse_feat[(size_t)p * 64 + c];

        // Phase A: point features -> bin sums (wave-per-point)
        for (int i = i0 + w; i < i1; i += 8) {
            const float* pt = pts + (size_t)i * 9;
            const float x = point_x(pt, wc);
            float y = fmaf(x, a_c, b_c);
            y = fmaxf(y, 0.f);
            const int bin = bov[vinv[i]];
            atomicAdd(&s_[bin][c], y + sf);
            if (lane == 0) atomicAdd(&scnt[bin], 1.f);
        }
        __syncthreads();

        // Phase B: bin means; also build transposed copy
        for (int idx = tid; idx < 2048; idx += 512) {
            const int b = idx >> 6, cc = idx & 63;
            const float m = s_[b][cc] / fmaxf(scnt[b], 1.f);
            s_[b][cc] = m;
            sT_[cc][b] = m;
        }
        __syncthreads();

        // Phase C: t = s@G, v = s@Wv. 4 rows per wave, lane = out channel.
        float at0 = 0.f, at1 = 0.f, at2 = 0.f, at3 = 0.f;
        float av0 = 0.f, av1 = 0.f, av2 = 0.f, av3 = 0.f;
#pragma unroll 2
        for (int kb = 0; kb < 64; kb += 4) {
            const float4 s0 = *(const float4*)&s_[r0 + 0][kb];
            const float4 s1 = *(const float4*)&s_[r0 + 1][kb];
            const float4 s2 = *(const float4*)&s_[r0 + 2][kb];
            const float4 s3 = *(const float4*)&s_[r0 + 3][kb];
            const float g0 = G_l[kb + 0][c], g1 = G_l[kb + 1][c];
            const float g2 = G_l[kb + 2][c], g3 = G_l[kb + 3][c];
            const float h0 = Wv_l[kb + 0][c], h1 = Wv_l[kb + 1][c];
            const float h2 = Wv_l[kb + 2][c], h3 = Wv_l[kb + 3][c];
            at0 = fmaf(s0.x, g0, at0); at0 = fmaf(s0.y, g1, at0);
            at0 = fmaf(s0.z, g2, at0); at0 = fmaf(s0.w, g3, at0);
            at1 = fmaf(s1.x, g0, at1); at1 = fmaf(s1.y, g1, at1);
            at1 = fmaf(s1.z, g2, at1); at1 = fmaf(s1.w, g3, at1);
            at2 = fmaf(s2.x, g0, at2); at2 = fmaf(s2.y, g1, at2);
            at2 = fmaf(s2.z, g2, at2); at2 = fmaf(s2.w, g3, at2);
            at3 = fmaf(s3.x, g0, at3); at3 = fmaf(s3.y, g1, at3);
            at3 = fmaf(s3.z, g2, at3); at3 = fmaf(s3.w, g3, at3);
            av0 = fmaf(s0.x, h0, av0); av0 = fmaf(s0.y, h1, av0);
            av0 = fmaf(s0.z, h2, av0); av0 = fmaf(s0.w, h3, av0);
            av1 = fmaf(s1.x, h0, av1); av1 = fmaf(s1.y, h1, av1);
            av1 = fmaf(s1.z, h2, av1); av1 = fmaf(s1.w, h3, av1);
            av2 = fmaf(s2.x, h0, av2); av2 = fmaf(s2.y, h1, av2);
            av2 = fmaf(s2.z, h2, av2); av2 = fmaf(s2.w, h3, av2);
            av3 = fmaf(s3.x, h0, av3); av3 = fmaf(s3.y, h1, av3);
            av3 = fmaf(s3.z, h2, av3); av3 = fmaf(s3.w, h3, av3);
        }
        t_[r0 + 0][c] = at0; t_[r0 + 1][c] = at1;
        t_[r0 + 2][c] = at2; t_[r0 + 3][c] = at3;
        v_[r0 + 0][c] = av0; v_[r0 + 1][c] = av1;
        v_[r0 + 2][c] = av2; v_[r0 + 3][c] = av3;
        __syncthreads();

        // Phase D: scores = t @ s^T, softmax over d (32 lanes per half).
        const int dd = lane & 31;
        const int half = lane >> 5;
        const int rA = r0 + half * 2;
        const int rB = rA + 1;
        float scA = 0.f, scB = 0.f;
#pragma unroll 2
        for (int cb = 0; cb < 64; cb += 4) {
            const float4 tA = *(const float4*)&t_[rA][cb];
            const float4 tB = *(const float4*)&t_[rB][cb];
            const float x0 = sT_[cb + 0][dd], x1 = sT_[cb + 1][dd];
            const float x2 = sT_[cb + 2][dd], x3 = sT_[cb + 3][dd];
            scA = fmaf(tA.x, x0, scA); scA = fmaf(tA.y, x1, scA);
            scA = fmaf(tA.z, x2, scA); scA = fmaf(tA.w, x3, scA);
            scB = fmaf(tB.x, x0, scB); scB = fmaf(tB.y, x1, scB);
            scB = fmaf(tB.z, x2, scB); scB = fmaf(tB.w, x3, scB);
        }
        {
            float mxA = scA, mxB = scB;
#pragma unroll
            for (int msk = 16; msk; msk >>= 1) {
                mxA = fmaxf(mxA, __shfl_xor(mxA, msk, 64));
                mxB = fmaxf(mxB, __shfl_xor(mxB, msk, 64));
            }
            const float eA = __expf(scA - mxA);
            const float eB = __expf(scB - mxB);
            float smA = eA, smB = eB;
#pragma unroll
            for (int msk = 16; msk; msk >>= 1) {
                smA += __shfl_xor(smA, msk, 64);
                smB += __shfl_xor(smB, msk, 64);
            }
            P_[rA][dd] = eA / smA;
            P_[rB][dd] = eB / smB;
        }
        __syncthreads();

        // Phase E: o = P v + s; pooled = max over bins
        float o0 = s_[r0 + 0][c], o1 = s_[r0 + 1][c];
        float o2 = s_[r0 + 2][c], o3 = s_[r0 + 3][c];
#pragma unroll 2
        for (int db = 0; db < 32; db += 4) {
            const float u0 = v_[db + 0][c], u1 = v_[db + 1][c];
            const float u2 = v_[db + 2][c], u3 = v_[db + 3][c];
            const float4 p0 = *(const float4*)&P_[r0 + 0][db];
            const float4 p1 = *(const float4*)&P_[r0 + 1][db];
            const float4 p2 = *(const float4*)&P_[r0 + 2][db];
            const float4 p3 = *(const float4*)&P_[r0 + 3][db];
            o0 = fmaf(p0.x, u0, o0); o0 = fmaf(p0.y, u1, o0);
            o0 = fmaf(p0.z, u2, o0); o0 = fmaf(p0.w, u3, o0);
            o1 = fmaf(p1.x, u0, o1); o1 = fmaf(p1.y, u1, o1);
            o1 = fmaf(p1.z, u2, o1); o1 = fmaf(p1.w, u3, o1);
            o2 = fmaf(p2.x, u0, o2); o2 = fmaf(p2.y, u1, o2);
            o2 = fmaf(p2.z, u2, o2); o2 = fmaf(p2.w, u3, o2);
            o3 = fmaf(p3.x, u0, o3); o3 = fmaf(p3.y, u1, o3);
            o3 = fmaf(p3.z, u2, o3); o3 = fmaf(p3.w, u3, o3);
        }
        const float pm = fmaxf(fmaxf(o0, o1), fmaxf(o2, o3));
        pool[w][c] = pm;
        __syncthreads();
        if (tid < 64) {
            float m0 = pool[0][tid];
#pragma unroll
            for (int ww = 1; ww < 8; ++ww) m0 = fmaxf(m0, pool[ww][tid]);
            out[(size_t)p * 64 + tid] = sf + m0;
        }
        __syncthreads();
    }
}

extern "C" void kernel_launch(void* const* d_in, const int* in_sizes, int n_in,
                              void* d_out, int out_size, void* d_ws, size_t ws_size,
                              hipStream_t stream)
{
    const float* pts         = (const float*)d_in[0];
    const float* sparse_feat = (const float*)d_in[1];
    const float* Wc          = (const float*)d_in[2];
    const float* gamma       = (const float*)d_in[3];
    const float* beta        = (const float*)d_in[4];
    const float* Wq          = (const float*)d_in[5];
    const float* Wk          = (const float*)d_in[6];
    const float* Wv          = (const float*)d_in[7];
    const int*   pinv        = (const int*)d_in[8];
    const int*   vinv        = (const int*)d_in[9];
    const int*   bov         = (const int*)d_in[11];
    const int*   occ         = (const int*)d_in[12];

    const int N = in_sizes[0] / 9;
    const int K = in_sizes[12];

    double* gsum = (double*)d_ws;            // 64 doubles
    double* gsq  = gsum + 64;                // 64 doubles
    float*  ab   = (float*)(gsum + 128);     // 128 floats
    float*  G    = ab + 128;                 // 4096 floats

    hipMemsetAsync(d_ws, 0, 128 * sizeof(double), stream);
    hipMemcpyAsync(d_out, sparse_feat, (size_t)out_size * sizeof(float),
                   hipMemcpyDeviceToDevice, stream);

    stats_kernel<<<1024, 256, 0, stream>>>(pts, Wc, gsum, gsq, N);
    prep_kernel<<<1, 256, 0, stream>>>(gsum, gsq, gamma, beta, Wq, Wk, ab, G, N);
    pillar_attn_kernel<<<1024, 512, 0, stream>>>(pts, sparse_feat, Wc, Wv,
                                                 pinv, vinv, bov, occ, ab, G,
                                                 (float*)d_out, N, K);
}